// Round 1
// baseline (968.479 us; speedup 1.0000x reference)
//
#include <hip/hip_runtime.h>
#include <math.h>

#define NB 256
#define NT 128
#define NDW 300
#define NH 128
#define NTYPE 8
#define NLEVEL 13
#define NN (NB*NT)

// int-workspace layout (in ints, at byte offset 32MB of d_ws)
#define CNT_N 0
#define OFF_N 16
#define FILL_N 32
#define CNT_E 48
#define OFF_E 160
#define FILL_E 272
#define NODE_LIST 512
#define EDGE_LIST (512+NN)

__global__ __launch_bounds__(256) void count_kernel(const int* __restrict__ parent,
    const int* __restrict__ dep_type, const int* __restrict__ height, int* ib) {
  int i = blockIdx.x*256 + threadIdx.x;
  if (i >= NN) return;
  atomicAdd(&ib[CNT_N + height[i]], 1);
  int p = parent[i];
  if (p >= 0) {
    int gp = (i & ~(NT-1)) + p;
    atomicAdd(&ib[CNT_E + height[gp]*NTYPE + dep_type[i]], 1);
  }
}

__global__ void scan_kernel(int* ib) {
  if (threadIdx.x != 0) return;
  int acc = 0;
  for (int k = 0; k < NLEVEL; k++) { ib[OFF_N+k]=acc; ib[FILL_N+k]=acc; acc += ib[CNT_N+k]; }
  ib[OFF_N+NLEVEL]=acc;
  acc = 0;
  for (int u = 0; u < NLEVEL*NTYPE; u++) { ib[OFF_E+u]=acc; ib[FILL_E+u]=acc; acc += ib[CNT_E+u]; }
  ib[OFF_E+NLEVEL*NTYPE]=acc;
}

__global__ __launch_bounds__(256) void scatter_kernel(const int* __restrict__ parent,
    const int* __restrict__ dep_type, const int* __restrict__ height, int* ib) {
  int i = blockIdx.x*256 + threadIdx.x;
  if (i >= NN) return;
  int pos = atomicAdd(&ib[FILL_N + height[i]], 1);
  ib[NODE_LIST + pos] = i;
  int p = parent[i];
  if (p >= 0) {
    int gp = (i & ~(NT-1)) + p;
    int pe = atomicAdd(&ib[FILL_E + height[gp]*NTYPE + dep_type[i]], 1);
    ib[EDGE_LIST + pe] = i;
  }
}

// wx = token_emb @ W_wh.T ; also zero hbuf (seg accumulator / output)
__global__ __launch_bounds__(128) void wx_kernel(const float* __restrict__ x,
    const float* __restrict__ Wwh, float* __restrict__ wx, float* __restrict__ hbuf) {
  __shared__ float sx[32][NDW];
  int block_row = blockIdx.x * 32;
  int tid = threadIdx.x;
  for (int idx = tid; idx < 32*NDW; idx += 128) {
    int r = idx / NDW, d = idx - r*NDW;
    sx[r][d] = x[(size_t)(block_row + r)*NDW + d];
  }
  __syncthreads();
  const float* wrow = Wwh + (size_t)tid*NDW;
  float acc[32];
  #pragma unroll
  for (int r = 0; r < 32; r++) acc[r] = 0.f;
  for (int d = 0; d < NDW; d++) {
    float w = wrow[d];
    #pragma unroll
    for (int r = 0; r < 32; r++) acc[r] += w * sx[r][d];
  }
  for (int r = 0; r < 32; r++) {
    wx[(size_t)(block_row+r)*NH + tid] = acc[r];
    hbuf[(size_t)(block_row+r)*NH + tid] = 0.f;
  }
}

// per level k: finalize h for nodes at height k, then g = W_hr @ h
__global__ __launch_bounds__(256) void node_kernel(const float* __restrict__ Whr,
    const float* __restrict__ wx, const float* __restrict__ bwh,
    const int* __restrict__ ib, float* __restrict__ hbuf, float* __restrict__ g, int k) {
  int start = ib[OFF_N+k], end = ib[OFF_N+k+1];
  if (start + (int)blockIdx.x*4 >= end) return;   // uniform early-exit before LDS stage
  __shared__ __align__(16) float sW[NH*132];
  __shared__ __align__(16) float sh[4][132];
  for (int idx = threadIdx.x; idx < NH*NH; idx += 256)
    sW[(idx>>7)*132 + (idx&127)] = Whr[idx];
  __syncthreads();
  int wave = threadIdx.x >> 6, lane = threadIdx.x & 63;
  int nw = gridDim.x * 4;
  for (int it = start + (int)blockIdx.x*4 + wave; it < end; it += nw) {
    int i = ib[NODE_LIST + it];
    const float* wxi = wx + (size_t)i*NH;
    float s0 = tanhf(wxi[lane]      + bwh[lane]);
    float s1 = tanhf(wxi[64+lane]   + bwh[64+lane]);
    float h0, h1;
    if (k == 0) { h0 = s0; h1 = s1; }
    else {
      h0 = tanhf(hbuf[(size_t)i*NH + lane]      + s0);
      h1 = tanhf(hbuf[(size_t)i*NH + 64 + lane] + s1);
    }
    hbuf[(size_t)i*NH + lane]      = h0;
    hbuf[(size_t)i*NH + 64 + lane] = h1;
    sh[wave][lane] = h0; sh[wave][64+lane] = h1;   // wave-synchronous LDS (in-order DS pipe)
    float g0 = 0.f, g1 = 0.f;
    #pragma unroll
    for (int d4 = 0; d4 < 32; d4++) {
      float4 hv = *(const float4*)&sh[wave][d4*4];
      float4 w0 = *(const float4*)&sW[lane*132 + d4*4];
      float4 w1 = *(const float4*)&sW[(lane+64)*132 + d4*4];
      g0 += w0.x*hv.x + w0.y*hv.y + w0.z*hv.z + w0.w*hv.w;
      g1 += w1.x*hv.x + w1.y*hv.y + w1.z*hv.z + w1.w*hv.w;
    }
    g[(size_t)i*NH + lane]      = g0;
    g[(size_t)i*NH + 64 + lane] = g1;
  }
}

// per level k: for edges whose parent is at height k (bucketed by type):
// infl = W_rel[t] @ tanh(g_child + wx_parent); atomically accumulate into hbuf[parent]
__global__ __launch_bounds__(256) void edge_kernel(const float* __restrict__ Wrel,
    const float* __restrict__ wx, const float* __restrict__ g,
    const int* __restrict__ parent, const int* __restrict__ ib,
    float* __restrict__ hbuf, int k) {
  const int ECHUNKS = 256, CH = 32;
  int t = blockIdx.x / ECHUNKS;
  int chunk = blockIdx.x - t*ECHUNKS;
  int bstart = ib[OFF_E + k*NTYPE + t];
  int bend   = ib[OFF_E + k*NTYPE + t + 1];
  if (bstart + chunk*CH >= bend) return;          // uniform early-exit before LDS stage
  __shared__ __align__(16) float sW[NH*132];
  __shared__ __align__(16) float sr[4][132];
  for (int idx = threadIdx.x; idx < NH*NH; idx += 256)
    sW[(idx>>7)*132 + (idx&127)] = Wrel[(size_t)t*NH*NH + idx];
  __syncthreads();
  int wave = threadIdx.x >> 6, lane = threadIdx.x & 63;
  for (int base = bstart + chunk*CH; base < bend; base += ECHUNKS*CH) {
    int lim = base + CH < bend ? base + CH : bend;
    for (int it = base + wave; it < lim; it += 4) {
      int c = ib[EDGE_LIST + it];
      int p = (c & ~(NT-1)) + parent[c];
      float r0 = tanhf(g[(size_t)c*NH + lane]      + wx[(size_t)p*NH + lane]);
      float r1 = tanhf(g[(size_t)c*NH + 64 + lane] + wx[(size_t)p*NH + 64 + lane]);
      sr[wave][lane] = r0; sr[wave][64+lane] = r1; // wave-synchronous LDS
      float i0 = 0.f, i1 = 0.f;
      #pragma unroll
      for (int d4 = 0; d4 < 32; d4++) {
        float4 rv = *(const float4*)&sr[wave][d4*4];
        float4 w0 = *(const float4*)&sW[lane*132 + d4*4];
        float4 w1 = *(const float4*)&sW[(lane+64)*132 + d4*4];
        i0 += w0.x*rv.x + w0.y*rv.y + w0.z*rv.z + w0.w*rv.w;
        i1 += w1.x*rv.x + w1.y*rv.y + w1.z*rv.z + w1.w*rv.w;
      }
      atomicAdd(&hbuf[(size_t)p*NH + lane],      i0);
      atomicAdd(&hbuf[(size_t)p*NH + 64 + lane], i1);
    }
  }
}

extern "C" void kernel_launch(void* const* d_in, const int* in_sizes, int n_in,
                              void* d_out, int out_size, void* d_ws, size_t ws_size,
                              hipStream_t stream) {
  const float* token  = (const float*)d_in[0];
  const float* Wwh    = (const float*)d_in[1];
  const float* bwh    = (const float*)d_in[2];
  const float* Whr    = (const float*)d_in[3];
  const float* Wrel   = (const float*)d_in[4];
  const int*   parent = (const int*)d_in[5];
  const int*   dep    = (const int*)d_in[6];
  const int*   height = (const int*)d_in[7];

  float* hbuf = (float*)d_out;                          // seg-accumulator, then final h
  float* wx   = (float*)d_ws;                           // [NN,NH] f32, 16MB
  float* g    = (float*)((char*)d_ws + 16777216);       // [NN,NH] f32, 16MB
  int*   ib   = (int*)((char*)d_ws + 33554432);         // bucket metadata + lists

  hipMemsetAsync(ib, 0, 2048, stream);                  // zero counters
  count_kernel<<<NN/256, 256, 0, stream>>>(parent, dep, height, ib);
  scan_kernel<<<1, 64, 0, stream>>>(ib);
  scatter_kernel<<<NN/256, 256, 0, stream>>>(parent, dep, height, ib);
  wx_kernel<<<NN/32, 128, 0, stream>>>(token, Wwh, wx, hbuf);
  node_kernel<<<1024, 256, 0, stream>>>(Whr, wx, bwh, ib, hbuf, g, 0);
  for (int k = 1; k < NLEVEL; k++) {
    edge_kernel<<<NTYPE*256, 256, 0, stream>>>(Wrel, wx, g, parent, ib, hbuf, k);
    node_kernel<<<1024, 256, 0, stream>>>(Whr, wx, bwh, ib, hbuf, g, k);
  }
}

// Round 2
// 488.811 us; speedup vs baseline: 1.9813x; 1.9813x over previous
//
#include <hip/hip_runtime.h>
#include <math.h>

#define NB 256
#define NT 128
#define NDW 300
#define NH 128
#define NTYPE 8
#define NLEVEL 13
#define NN (NB*NT)

#define NBK 117       // 13 node buckets + 104 edge buckets
#define CBLOCKS 64

// ib layout (ints), at byte offset 32MB of d_ws
#define BC 0                    // [CBLOCKS][NBK] per-block counts
#define BB 8192                 // [CBLOCKS][NBK] per-block base offsets
#define OFF_N 16384             // [14] node-level starts
#define OFF_E 16400             // [105] edge (level,type) starts
#define NODE_LIST 16512
#define EDGE_LIST (16512+NN)

__global__ __launch_bounds__(256) void count_kernel(const int* __restrict__ parent,
    const int* __restrict__ dep_type, const int* __restrict__ height, int* ib) {
  __shared__ int cnt[NBK];
  for (int u = threadIdx.x; u < NBK; u += 256) cnt[u] = 0;
  __syncthreads();
  for (int i = blockIdx.x*256 + threadIdx.x; i < NN; i += CBLOCKS*256) {
    atomicAdd(&cnt[height[i]], 1);
    int p = parent[i];
    if (p >= 0) {
      int gp = (i & ~(NT-1)) + p;
      atomicAdd(&cnt[13 + height[gp]*NTYPE + dep_type[i]], 1);
    }
  }
  __syncthreads();
  for (int u = threadIdx.x; u < NBK; u += 256)
    ib[BC + blockIdx.x*NBK + u] = cnt[u];
}

__global__ __launch_bounds__(128) void scan_kernel(int* ib) {
  __shared__ int total[NBK], start[NBK];
  int u = threadIdx.x;
  if (u < NBK) {
    int acc = 0;
    for (int b = 0; b < CBLOCKS; b++) {
      ib[BB + b*NBK + u] = acc;
      acc += ib[BC + b*NBK + u];
    }
    total[u] = acc;
  }
  __syncthreads();
  if (u == 0) {
    int acc = 0;
    for (int k = 0; k < 13; k++) { start[k] = acc; ib[OFF_N+k] = acc; acc += total[k]; }
    ib[OFF_N+13] = acc;
    acc = 0;
    for (int e = 0; e < 104; e++) { start[13+e] = acc; ib[OFF_E+e] = acc; acc += total[13+e]; }
    ib[OFF_E+104] = acc;
  }
  __syncthreads();
  if (u < NBK) {
    int s = start[u];
    for (int b = 0; b < CBLOCKS; b++) ib[BB + b*NBK + u] += s;
  }
}

__global__ __launch_bounds__(256) void scatter_kernel(const int* __restrict__ parent,
    const int* __restrict__ dep_type, const int* __restrict__ height, int* ib) {
  __shared__ int base[NBK];
  __shared__ int cnt[NBK];
  for (int u = threadIdx.x; u < NBK; u += 256) {
    base[u] = ib[BB + blockIdx.x*NBK + u];
    cnt[u] = 0;
  }
  __syncthreads();
  for (int i = blockIdx.x*256 + threadIdx.x; i < NN; i += CBLOCKS*256) {
    int hb = height[i];
    int pos = atomicAdd(&cnt[hb], 1);
    ib[NODE_LIST + base[hb] + pos] = i;
    int p = parent[i];
    if (p >= 0) {
      int gp = (i & ~(NT-1)) + p;
      int eb = 13 + height[gp]*NTYPE + dep_type[i];
      int pe = atomicAdd(&cnt[eb], 1);
      ib[EDGE_LIST + base[eb] + pe] = i;
    }
  }
}

// wx = token_emb @ W_wh.T ; also zero hbuf (seg accumulator / output)
__global__ __launch_bounds__(128) void wx_kernel(const float* __restrict__ x,
    const float* __restrict__ Wwh, float* __restrict__ wx, float* __restrict__ hbuf) {
  __shared__ float sx[32][NDW];
  int block_row = blockIdx.x * 32;
  int tid = threadIdx.x;
  for (int idx = tid; idx < 32*NDW; idx += 128) {
    int r = idx / NDW, d = idx - r*NDW;
    sx[r][d] = x[(size_t)(block_row + r)*NDW + d];
  }
  __syncthreads();
  const float* wrow = Wwh + (size_t)tid*NDW;
  float acc[32];
  #pragma unroll
  for (int r = 0; r < 32; r++) acc[r] = 0.f;
  for (int d = 0; d < NDW; d++) {
    float w = wrow[d];
    #pragma unroll
    for (int r = 0; r < 32; r++) acc[r] += w * sx[r][d];
  }
  for (int r = 0; r < 32; r++) {
    wx[(size_t)(block_row+r)*NH + tid] = acc[r];
    hbuf[(size_t)(block_row+r)*NH + tid] = 0.f;
  }
}

// per level k: finalize h for nodes at height k, then g = W_hr @ h
__global__ __launch_bounds__(256) void node_kernel(const float* __restrict__ Whr,
    const float* __restrict__ wx, const float* __restrict__ bwh,
    const int* __restrict__ ib, float* __restrict__ hbuf, float* __restrict__ g, int k) {
  int start = ib[OFF_N+k], end = ib[OFF_N+k+1];
  if (start + (int)blockIdx.x*4 >= end) return;   // uniform early-exit before LDS stage
  __shared__ __align__(16) float sW[NH*132];
  __shared__ __align__(16) float sh[4][132];
  for (int idx = threadIdx.x; idx < NH*NH; idx += 256)
    sW[(idx>>7)*132 + (idx&127)] = Whr[idx];
  __syncthreads();
  int wave = threadIdx.x >> 6, lane = threadIdx.x & 63;
  int nw = gridDim.x * 4;
  for (int it = start + (int)blockIdx.x*4 + wave; it < end; it += nw) {
    int i = ib[NODE_LIST + it];
    const float* wxi = wx + (size_t)i*NH;
    float s0 = tanhf(wxi[lane]      + bwh[lane]);
    float s1 = tanhf(wxi[64+lane]   + bwh[64+lane]);
    float h0, h1;
    if (k == 0) { h0 = s0; h1 = s1; }
    else {
      h0 = tanhf(hbuf[(size_t)i*NH + lane]      + s0);
      h1 = tanhf(hbuf[(size_t)i*NH + 64 + lane] + s1);
    }
    hbuf[(size_t)i*NH + lane]      = h0;
    hbuf[(size_t)i*NH + 64 + lane] = h1;
    sh[wave][lane] = h0; sh[wave][64+lane] = h1;   // wave-synchronous LDS (in-order DS pipe)
    float g0 = 0.f, g1 = 0.f;
    #pragma unroll
    for (int d4 = 0; d4 < 32; d4++) {
      float4 hv = *(const float4*)&sh[wave][d4*4];
      float4 w0 = *(const float4*)&sW[lane*132 + d4*4];
      float4 w1 = *(const float4*)&sW[(lane+64)*132 + d4*4];
      g0 += w0.x*hv.x + w0.y*hv.y + w0.z*hv.z + w0.w*hv.w;
      g1 += w1.x*hv.x + w1.y*hv.y + w1.z*hv.z + w1.w*hv.w;
    }
    g[(size_t)i*NH + lane]      = g0;
    g[(size_t)i*NH + 64 + lane] = g1;
  }
}

// per level k: for edges whose parent is at height k (bucketed by type):
// infl = W_rel[t] @ tanh(g_child + wx_parent); atomically accumulate into hbuf[parent]
__global__ __launch_bounds__(256) void edge_kernel(const float* __restrict__ Wrel,
    const float* __restrict__ wx, const float* __restrict__ g,
    const int* __restrict__ parent, const int* __restrict__ ib,
    float* __restrict__ hbuf, int k) {
  const int ECHUNKS = 256, CH = 32;
  int t = blockIdx.x / ECHUNKS;
  int chunk = blockIdx.x - t*ECHUNKS;
  int bstart = ib[OFF_E + k*NTYPE + t];
  int bend   = ib[OFF_E + k*NTYPE + t + 1];
  if (bstart + chunk*CH >= bend) return;          // uniform early-exit before LDS stage
  __shared__ __align__(16) float sW[NH*132];
  __shared__ __align__(16) float sr[4][132];
  for (int idx = threadIdx.x; idx < NH*NH; idx += 256)
    sW[(idx>>7)*132 + (idx&127)] = Wrel[(size_t)t*NH*NH + idx];
  __syncthreads();
  int wave = threadIdx.x >> 6, lane = threadIdx.x & 63;
  for (int base = bstart + chunk*CH; base < bend; base += ECHUNKS*CH) {
    int lim = base + CH < bend ? base + CH : bend;
    for (int it = base + wave; it < lim; it += 4) {
      int c = ib[EDGE_LIST + it];
      int p = (c & ~(NT-1)) + parent[c];
      float r0 = tanhf(g[(size_t)c*NH + lane]      + wx[(size_t)p*NH + lane]);
      float r1 = tanhf(g[(size_t)c*NH + 64 + lane] + wx[(size_t)p*NH + 64 + lane]);
      sr[wave][lane] = r0; sr[wave][64+lane] = r1; // wave-synchronous LDS
      float i0 = 0.f, i1 = 0.f;
      #pragma unroll
      for (int d4 = 0; d4 < 32; d4++) {
        float4 rv = *(const float4*)&sr[wave][d4*4];
        float4 w0 = *(const float4*)&sW[lane*132 + d4*4];
        float4 w1 = *(const float4*)&sW[(lane+64)*132 + d4*4];
        i0 += w0.x*rv.x + w0.y*rv.y + w0.z*rv.z + w0.w*rv.w;
        i1 += w1.x*rv.x + w1.y*rv.y + w1.z*rv.z + w1.w*rv.w;
      }
      atomicAdd(&hbuf[(size_t)p*NH + lane],      i0);
      atomicAdd(&hbuf[(size_t)p*NH + 64 + lane], i1);
    }
  }
}

extern "C" void kernel_launch(void* const* d_in, const int* in_sizes, int n_in,
                              void* d_out, int out_size, void* d_ws, size_t ws_size,
                              hipStream_t stream) {
  const float* token  = (const float*)d_in[0];
  const float* Wwh    = (const float*)d_in[1];
  const float* bwh    = (const float*)d_in[2];
  const float* Whr    = (const float*)d_in[3];
  const float* Wrel   = (const float*)d_in[4];
  const int*   parent = (const int*)d_in[5];
  const int*   dep    = (const int*)d_in[6];
  const int*   height = (const int*)d_in[7];

  float* hbuf = (float*)d_out;                          // seg-accumulator, then final h
  float* wx   = (float*)d_ws;                           // [NN,NH] f32, 16MB
  float* g    = (float*)((char*)d_ws + 16777216);       // [NN,NH] f32, 16MB
  int*   ib   = (int*)((char*)d_ws + 33554432);         // bucket metadata + lists

  count_kernel<<<CBLOCKS, 256, 0, stream>>>(parent, dep, height, ib);
  scan_kernel<<<1, 128, 0, stream>>>(ib);
  scatter_kernel<<<CBLOCKS, 256, 0, stream>>>(parent, dep, height, ib);
  wx_kernel<<<NN/32, 128, 0, stream>>>(token, Wwh, wx, hbuf);
  node_kernel<<<1024, 256, 0, stream>>>(Whr, wx, bwh, ib, hbuf, g, 0);
  for (int k = 1; k < NLEVEL; k++) {
    edge_kernel<<<NTYPE*256, 256, 0, stream>>>(Wrel, wx, g, parent, ib, hbuf, k);
    node_kernel<<<1024, 256, 0, stream>>>(Whr, wx, bwh, ib, hbuf, g, k);
  }
}